// Round 1
// baseline (926.276 us; speedup 1.0000x reference)
//
#include <hip/hip_runtime.h>
#include <math.h>

#define TT 2
#define CC 64
#define HH 160
#define WW 160
#define KS 7
#define K2 49
#define NSPIX 196
#define HWSZ (HH*WW)
#define PAD 3
#define OO 64
#define FANIN (CC*K2)
#define TS 8
#define PS (TS+KS-1)   // 14

__device__ __forceinline__ int reflect(int i, int n) {
    if (i < 0) i = -i;
    if (i >= n) i = 2*n - 2 - i;
    return i;
}

// W_lin[o][ck] -> Wt[ck][o]
__global__ void k_wt(const float* __restrict__ Wl, float* __restrict__ Wt) {
    int tid = blockIdx.x*256 + threadIdx.x;
    if (tid >= OO*FANIN) return;
    int ck = tid >> 6;
    int o  = tid & 63;
    Wt[tid] = Wl[o*FANIN + ck];
}

// segment sums + counts via atomics
__global__ void k_seg(const float* __restrict__ x, const int* __restrict__ spix,
                      float* __restrict__ sums, float* __restrict__ cnts) {
    int pix = blockIdx.x*256 + threadIdx.x;
    if (pix >= TT*HWSZ) return;
    int t = pix / HWSZ, hw = pix - t*HWSZ;
    int s = spix[pix];
    float* dst = sums + (t*NSPIX + s)*CC;
    const float* xs = x + (size_t)t*CC*HWSZ + hw;
    #pragma unroll 4
    for (int c = 0; c < CC; ++c) atomicAdd(&dst[c], xs[c*HWSZ]);
    atomicAdd(&cnts[t*NSPIX + s], 1.0f);
}

// down = sums/max(cnt,1); sq = sum(down^2)
__global__ void k_down(const float* __restrict__ sums, const float* __restrict__ cnts,
                       float* __restrict__ down, float* __restrict__ sq) {
    int ts = blockIdx.x; int c = threadIdx.x;
    float cnt = fmaxf(cnts[ts], 1.0f);
    float d = sums[ts*CC + c] / cnt;
    down[ts*CC + c] = d;
    float v = d*d;
    for (int off = 32; off; off >>= 1) v += __shfl_down(v, off, 64);
    if (c == 0) sq[ts] = v;
}

// pwd[t,s,u] = max(sq_s + sq_u - 2 dot, 0)
__global__ void k_pwd(const float* __restrict__ down, const float* __restrict__ sq,
                      float* __restrict__ pwd) {
    int tid = blockIdx.x*256 + threadIdx.x;
    if (tid >= TT*NSPIX*NSPIX) return;
    int t = tid / (NSPIX*NSPIX); int r = tid - t*NSPIX*NSPIX;
    int s = r / NSPIX, u = r - (r / NSPIX)*NSPIX;
    const float* ds = down + (t*NSPIX + s)*CC;
    const float* du = down + (t*NSPIX + u)*CC;
    float dot = 0.f;
    #pragma unroll 4
    for (int c = 0; c < CC; ++c) dot += ds[c]*du[c];
    float v = sq[t*NSPIX + s] + sq[t*NSPIX + u] - 2.f*dot;
    pwd[tid] = fmaxf(v, 0.f);
}

// per-pixel scale = 10*softplus(dot(w, x)/(||x||+1e-10) + b)
__global__ void k_scale(const float* __restrict__ x, const float* __restrict__ wsc,
                        const float* __restrict__ bsc, float* __restrict__ scale) {
    int pix = blockIdx.x*256 + threadIdx.x;
    if (pix >= TT*HWSZ) return;
    int t = pix / HWSZ, hw = pix - t*HWSZ;
    const float* xs = x + (size_t)t*CC*HWSZ + hw;
    float s1 = 0.f, s2 = 0.f;
    #pragma unroll 4
    for (int c = 0; c < CC; ++c) { float v = xs[c*HWSZ]; s1 += wsc[c]*v; s2 += v*v; }
    float z = s1/(sqrtf(s2) + 1e-10f) + bsc[0];
    float sp = (z > 0.f) ? z + log1pf(expf(-z)) : log1pf(expf(z));
    scale[pix] = 10.f*sp;
}

// main: 8x8 pixel tile per block; block (64,4): wave q owns o in [16q,16q+16)
__global__ __launch_bounds__(256, 2) void k_main(
    const float* __restrict__ x, const int* __restrict__ spix,
    const float* __restrict__ Wt, const float* __restrict__ b_lin,
    const float* __restrict__ pwd, const float* __restrict__ scale,
    float* __restrict__ out)
{
    __shared__ float xp[CC*PS*PS];   // 50176 B
    __shared__ float rw[K2*64];      // 12544 B
    __shared__ int   sp[PS*PS];      // 784 B
    __shared__ float mxl[64];        // 256 B

    int bid = blockIdx.x;
    int t = bid / ((HH/TS)*(WW/TS));
    int r = bid - t*((HH/TS)*(WW/TS));
    int th0 = (r / (WW/TS))*TS, tw0 = (r - (r/(WW/TS))*(WW/TS))*TS;
    int tid = threadIdx.y*64 + threadIdx.x;

    for (int i = tid; i < PS*PS; i += 256) {
        int rr = reflect(th0 + i/PS - PAD, HH);
        int cc = reflect(tw0 + i%PS - PAD, WW);
        sp[i] = spix[t*HWSZ + rr*WW + cc];
    }
    for (int i = tid; i < CC*PS*PS; i += 256) {
        int c = i / (PS*PS); int pq = i - c*(PS*PS);
        int rr = reflect(th0 + pq/PS - PAD, HH);
        int cc = reflect(tw0 + pq%PS - PAD, WW);
        xp[i] = x[((size_t)t*CC + c)*HWSZ + rr*WW + cc];
    }
    __syncthreads();

    int p = threadIdx.x;
    int py = p >> 3, px = p & 7;
    int h = th0 + py, w = tw0 + px;
    float sc = scale[t*HWSZ + h*WW + w];
    int s0 = sp[(py+PAD)*PS + (px+PAD)];
    const float* pr = pwd + (t*NSPIX + s0)*NSPIX;

    for (int k = threadIdx.y; k < K2; k += 4) {
        int di = k/KS, dj = k - di*KS;
        int nb = sp[(py+di)*PS + (px+dj)];
        rw[k*64 + p] = expf(-sc * pr[nb]);
    }
    __syncthreads();
    if (threadIdx.y == 0) {
        float m = 0.f;
        for (int k = 0; k < K2; ++k) m = fmaxf(m, rw[k*64 + p]);
        mxl[p] = 1.f/(1e-5f + m);
    }
    __syncthreads();
    for (int k = threadIdx.y; k < K2; k += 4) rw[k*64 + p] *= mxl[p];
    __syncthreads();

    // wave-uniform o-slice base (force SGPR so W loads become s_load)
    int q = __builtin_amdgcn_readfirstlane(threadIdx.y);
    const float* wtq = Wt + q*16;

    float acc[16];
    #pragma unroll
    for (int j = 0; j < 16; ++j) acc[j] = 0.f;

    for (int k = 0; k < K2; ++k) {
        int di = k/KS, dj = k - di*KS;
        const float* xk = xp + (py+di)*PS + (px+dj);
        float rwv = rw[k*64 + p];
        const float* wk = wtq + k*64;
        #pragma unroll 4
        for (int c = 0; c < CC; ++c) {
            float val = rwv * xk[c*(PS*PS)];
            const float* wc = wk + c*(K2*64);
            #pragma unroll
            for (int j = 0; j < 16; ++j) acc[j] = fmaf(wc[j], val, acc[j]);
        }
    }

    int obase = q*16;
    #pragma unroll
    for (int j = 0; j < 16; ++j) {
        int o = obase + j;
        out[(((size_t)t*OO + o)*HH + h)*WW + w] = acc[j] + b_lin[o];
    }
}

extern "C" void kernel_launch(void* const* d_in, const int* in_sizes, int n_in,
                              void* d_out, int out_size, void* d_ws, size_t ws_size,
                              hipStream_t stream) {
    const float* x    = (const float*)d_in[0];
    const int*   spix = (const int*)d_in[1];
    const float* Wl   = (const float*)d_in[2];
    const float* bl   = (const float*)d_in[3];
    const float* wsc  = (const float*)d_in[4];
    const float* bsc  = (const float*)d_in[5];
    float* out = (float*)d_out;

    float* ws    = (float*)d_ws;
    float* sums  = ws;                          // 25088
    float* cnts  = sums + TT*NSPIX*CC;          // 392
    float* down  = cnts + TT*NSPIX;             // 25088
    float* sq    = down + TT*NSPIX*CC;          // 392
    float* pwd   = sq   + TT*NSPIX;             // 76832
    float* scale = pwd  + TT*NSPIX*NSPIX;       // 51200
    float* Wt    = scale + TT*HWSZ;             // 200704

    hipMemsetAsync(sums, 0, (size_t)(TT*NSPIX*CC + TT*NSPIX)*sizeof(float), stream);

    k_wt  <<<(OO*FANIN + 255)/256, 256, 0, stream>>>(Wl, Wt);
    k_seg <<<(TT*HWSZ + 255)/256, 256, 0, stream>>>(x, spix, sums, cnts);
    k_down<<<TT*NSPIX, 64, 0, stream>>>(sums, cnts, down, sq);
    k_pwd <<<(TT*NSPIX*NSPIX + 255)/256, 256, 0, stream>>>(down, sq, pwd);
    k_scale<<<(TT*HWSZ + 255)/256, 256, 0, stream>>>(x, wsc, bsc, scale);

    dim3 blk(64, 4, 1);
    k_main<<<TT*(HH/TS)*(WW/TS), blk, 0, stream>>>(x, spix, Wt, bl, pwd, scale, out);
}

// Round 2
// 761.729 us; speedup vs baseline: 1.2160x; 1.2160x over previous
//
#include <hip/hip_runtime.h>
#include <math.h>

#define TT 2
#define CC 64
#define HH 160
#define WW 160
#define KS 7
#define K2 49
#define NSPIX 196
#define HWSZ (HH*WW)
#define PAD 3
#define OO 64
#define FANIN (CC*K2)
#define TS 8
#define PS (TS+KS-1)   // 14
#define CHALF 32

__device__ __forceinline__ int reflect(int i, int n) {
    if (i < 0) i = -i;
    if (i >= n) i = 2*n - 2 - i;
    return i;
}

// W_lin[o][ck] -> Wt[ck][o]
__global__ void k_wt(const float* __restrict__ Wl, float* __restrict__ Wt) {
    int tid = blockIdx.x*256 + threadIdx.x;
    if (tid >= OO*FANIN) return;
    int ck = tid >> 6;
    int o  = tid & 63;
    Wt[tid] = Wl[o*FANIN + ck];
}

// two-stage segment sums: LDS accumulate per block, then flush with global atomics
#define SEG_CHUNK 1024
#define SEG_BLKS_PER_T (HWSZ/SEG_CHUNK)   // 50
__global__ __launch_bounds__(256) void k_seg(const float* __restrict__ x,
                                             const int* __restrict__ spix,
                                             float* __restrict__ sums,
                                             float* __restrict__ cnts) {
    __shared__ float ls[CC*200];   // [c][200] — random s spreads banks
    __shared__ float lc[NSPIX];
    int tid = threadIdx.x;
    for (int i = tid; i < CC*200; i += 256) ls[i] = 0.f;
    for (int i = tid; i < NSPIX; i += 256) lc[i] = 0.f;
    __syncthreads();

    int t = blockIdx.x / SEG_BLKS_PER_T;
    int chunk = blockIdx.x - t*SEG_BLKS_PER_T;
    int base = chunk*SEG_CHUNK;
    for (int i = tid; i < SEG_CHUNK; i += 256) {
        int hw = base + i;
        int s = spix[t*HWSZ + hw];
        atomicAdd(&lc[s], 1.0f);
        const float* xs = x + (size_t)t*CC*HWSZ + hw;
        #pragma unroll 4
        for (int c = 0; c < CC; ++c) atomicAdd(&ls[c*200 + s], xs[c*HWSZ]);
    }
    __syncthreads();
    for (int i = tid; i < CC*NSPIX; i += 256) {
        int c = i / NSPIX, s = i - c*NSPIX;   // lanes: consecutive s -> conflict-free LDS
        float v = ls[c*200 + s];
        if (v != 0.f) atomicAdd(&sums[(t*NSPIX + s)*CC + c], v);
    }
    for (int i = tid; i < NSPIX; i += 256) {
        float v = lc[i];
        if (v != 0.f) atomicAdd(&cnts[t*NSPIX + i], v);
    }
}

// down = sums/max(cnt,1); sq = sum(down^2)
__global__ void k_down(const float* __restrict__ sums, const float* __restrict__ cnts,
                       float* __restrict__ down, float* __restrict__ sq) {
    int ts = blockIdx.x; int c = threadIdx.x;
    float cnt = fmaxf(cnts[ts], 1.0f);
    float d = sums[ts*CC + c] / cnt;
    down[ts*CC + c] = d;
    float v = d*d;
    for (int off = 32; off; off >>= 1) v += __shfl_down(v, off, 64);
    if (c == 0) sq[ts] = v;
}

// pwd[t,s,u] = max(sq_s + sq_u - 2 dot, 0)
__global__ void k_pwd(const float* __restrict__ down, const float* __restrict__ sq,
                      float* __restrict__ pwd) {
    int tid = blockIdx.x*256 + threadIdx.x;
    if (tid >= TT*NSPIX*NSPIX) return;
    int t = tid / (NSPIX*NSPIX); int r = tid - t*NSPIX*NSPIX;
    int s = r / NSPIX, u = r - (r / NSPIX)*NSPIX;
    const float* ds = down + (t*NSPIX + s)*CC;
    const float* du = down + (t*NSPIX + u)*CC;
    float dot = 0.f;
    #pragma unroll 4
    for (int c = 0; c < CC; ++c) dot += ds[c]*du[c];
    float v = sq[t*NSPIX + s] + sq[t*NSPIX + u] - 2.f*dot;
    pwd[tid] = fmaxf(v, 0.f);
}

// per-pixel scale = 10*softplus(dot(w, x)/(||x||+1e-10) + b)
__global__ void k_scale(const float* __restrict__ x, const float* __restrict__ wsc,
                        const float* __restrict__ bsc, float* __restrict__ scale) {
    int pix = blockIdx.x*256 + threadIdx.x;
    if (pix >= TT*HWSZ) return;
    int t = pix / HWSZ, hw = pix - t*HWSZ;
    const float* xs = x + (size_t)t*CC*HWSZ + hw;
    float s1 = 0.f, s2 = 0.f;
    #pragma unroll 4
    for (int c = 0; c < CC; ++c) { float v = xs[c*HWSZ]; s1 += wsc[c]*v; s2 += v*v; }
    float z = s1/(sqrtf(s2) + 1e-10f) + bsc[0];
    float sp = (z > 0.f) ? z + log1pf(expf(-z)) : log1pf(expf(z));
    scale[pix] = 10.f*sp;
}

// main: 8x8 pixel tile per block; block (64,4): wave q owns o in [16q,16q+16)
// channels staged in two halves of 32 so LDS = ~38.7 KB -> 4 blocks/CU.
__global__ __launch_bounds__(256, 4) void k_main(
    const float* __restrict__ x, const int* __restrict__ spix,
    const float* __restrict__ Wt, const float* __restrict__ b_lin,
    const float* __restrict__ pwd, const float* __restrict__ scale,
    float* __restrict__ out)
{
    __shared__ float xp[CHALF*PS*PS];  // 25088 B
    __shared__ float rw[K2*64];        // 12544 B
    __shared__ int   sp[PS*PS];        // 784 B
    __shared__ float mxl[64];          // 256 B

    int bid = blockIdx.x;
    int t = bid / ((HH/TS)*(WW/TS));
    int r = bid - t*((HH/TS)*(WW/TS));
    int th0 = (r / (WW/TS))*TS, tw0 = (r - (r/(WW/TS))*(WW/TS))*TS;
    int tid = threadIdx.y*64 + threadIdx.x;

    for (int i = tid; i < PS*PS; i += 256) {
        int rr = reflect(th0 + i/PS - PAD, HH);
        int cc = reflect(tw0 + i%PS - PAD, WW);
        sp[i] = spix[t*HWSZ + rr*WW + cc];
    }
    __syncthreads();

    int p = threadIdx.x;
    int py = p >> 3, px = p & 7;
    int h = th0 + py, w = tw0 + px;
    float sc = scale[t*HWSZ + h*WW + w];
    int s0 = sp[(py+PAD)*PS + (px+PAD)];
    const float* pr = pwd + (t*NSPIX + s0)*NSPIX;

    for (int k = threadIdx.y; k < K2; k += 4) {
        int di = k/KS, dj = k - di*KS;
        int nb = sp[(py+di)*PS + (px+dj)];
        rw[k*64 + p] = expf(-sc * pr[nb]);
    }
    __syncthreads();
    if (threadIdx.y == 0) {
        float m = 0.f;
        for (int k = 0; k < K2; ++k) m = fmaxf(m, rw[k*64 + p]);
        mxl[p] = 1.f/(1e-5f + m);
    }
    __syncthreads();
    for (int k = threadIdx.y; k < K2; k += 4) rw[k*64 + p] *= mxl[p];

    // wave-uniform o-slice base (force SGPR so W loads become s_load)
    int q = __builtin_amdgcn_readfirstlane(threadIdx.y);

    float acc[16];
    #pragma unroll
    for (int j = 0; j < 16; ++j) acc[j] = 0.f;

    for (int half = 0; half < 2; ++half) {
        __syncthreads();   // protect xp (and, for half 0, rw writes above)
        for (int i = tid; i < CHALF*PS*PS; i += 256) {
            int c = i / (PS*PS); int pq = i - c*(PS*PS);
            int rr = reflect(th0 + pq/PS - PAD, HH);
            int cc = reflect(tw0 + pq%PS - PAD, WW);
            xp[i] = x[((size_t)t*CC + half*CHALF + c)*HWSZ + rr*WW + cc];
        }
        __syncthreads();

        const float* wq = Wt + q*16 + (size_t)half*CHALF*K2*64;
        for (int k = 0; k < K2; ++k) {
            int di = k/KS, dj = k - di*KS;
            const float* xk = xp + (py+di)*PS + (px+dj);
            float rwv = rw[k*64 + p];
            const float* wk = wq + k*64;
            #pragma unroll 8
            for (int c = 0; c < CHALF; ++c) {
                float val = rwv * xk[c*(PS*PS)];
                const float* wc = wk + c*(K2*64);
                #pragma unroll
                for (int j = 0; j < 16; ++j) acc[j] = fmaf(wc[j], val, acc[j]);
            }
        }
    }

    int obase = q*16;
    #pragma unroll
    for (int j = 0; j < 16; ++j) {
        int o = obase + j;
        out[(((size_t)t*OO + o)*HH + h)*WW + w] = acc[j] + b_lin[o];
    }
}

extern "C" void kernel_launch(void* const* d_in, const int* in_sizes, int n_in,
                              void* d_out, int out_size, void* d_ws, size_t ws_size,
                              hipStream_t stream) {
    const float* x    = (const float*)d_in[0];
    const int*   spix = (const int*)d_in[1];
    const float* Wl   = (const float*)d_in[2];
    const float* bl   = (const float*)d_in[3];
    const float* wsc  = (const float*)d_in[4];
    const float* bsc  = (const float*)d_in[5];
    float* out = (float*)d_out;

    float* ws    = (float*)d_ws;
    float* sums  = ws;                          // 25088
    float* cnts  = sums + TT*NSPIX*CC;          // 392
    float* down  = cnts + TT*NSPIX;             // 25088
    float* sq    = down + TT*NSPIX*CC;          // 392
    float* pwd   = sq   + TT*NSPIX;             // 76832
    float* scale = pwd  + TT*NSPIX*NSPIX;       // 51200
    float* Wt    = scale + TT*HWSZ;             // 200704

    hipMemsetAsync(sums, 0, (size_t)(TT*NSPIX*CC + TT*NSPIX)*sizeof(float), stream);

    k_wt  <<<(OO*FANIN + 255)/256, 256, 0, stream>>>(Wl, Wt);
    k_seg <<<TT*SEG_BLKS_PER_T, 256, 0, stream>>>(x, spix, sums, cnts);
    k_down<<<TT*NSPIX, 64, 0, stream>>>(sums, cnts, down, sq);
    k_pwd <<<(TT*NSPIX*NSPIX + 255)/256, 256, 0, stream>>>(down, sq, pwd);
    k_scale<<<(TT*HWSZ + 255)/256, 256, 0, stream>>>(x, wsc, bsc, scale);

    dim3 blk(64, 4, 1);
    k_main<<<TT*(HH/TS)*(WW/TS), blk, 0, stream>>>(x, spix, Wt, bl, pwd, scale, out);
}

// Round 3
// 268.056 us; speedup vs baseline: 3.4555x; 2.8417x over previous
//
#include <hip/hip_runtime.h>
#include <math.h>

#define TT 2
#define CC 64
#define HH 160
#define WW 160
#define KS 7
#define K2 49
#define NSPIX 196
#define HWSZ (HH*WW)
#define PAD 3
#define OO 64
#define FANIN (CC*K2)
#define TS 8
#define PS (TS+KS-1)   // 14
#define NPOS (PS*PS)   // 196
#define XROW 72        // bf16 elems per padded row (144 B: 16B-aligned, stride-4 banks)

typedef short short8 __attribute__((ext_vector_type(8)));
typedef float f32x16 __attribute__((ext_vector_type(16)));

__device__ __forceinline__ int reflect(int i, int n) {
    if (i < 0) i = -i;
    if (i >= n) i = 2*n - 2 - i;
    return i;
}

__device__ __forceinline__ unsigned short f2bf(float f) {
    unsigned int u = __float_as_uint(f);
    unsigned int r = (u + 0x7FFFu + ((u >> 16) & 1u)) >> 16;
    return (unsigned short)r;
}
__device__ __forceinline__ float bf2f(unsigned short s) {
    return __uint_as_float(((unsigned int)s) << 16);
}

// Build Wb in 32x32x16 bf16 A-fragment order:
// flat = (((qo*49+tap)*4+kc)*64+ln)*8+j ; o=qo*32+(ln&31); c=kc*16+(ln>>5)*8+j
// value = W_lin[o][c*49+tap]
__global__ void k_wb(const float* __restrict__ Wl, unsigned short* __restrict__ Wb) {
    int idx = blockIdx.x*256 + threadIdx.x;
    if (idx >= 2*K2*4*64*8) return;
    int j   = idx & 7;
    int ln  = (idx >> 3) & 63;
    int kc  = (idx >> 9) & 3;
    int tap = (idx >> 11) % K2;
    int qo  = idx / (K2 << 11);
    int o = qo*32 + (ln & 31);
    int c = kc*16 + (ln >> 5)*8 + j;
    Wb[idx] = f2bf(Wl[o*FANIN + c*K2 + tap]);
}

// two-stage segment sums: LDS accumulate per block, then flush with global atomics
#define SEG_CHUNK 1024
#define SEG_BLKS_PER_T (HWSZ/SEG_CHUNK)   // 50
__global__ __launch_bounds__(256) void k_seg(const float* __restrict__ x,
                                             const int* __restrict__ spix,
                                             float* __restrict__ sums,
                                             float* __restrict__ cnts) {
    __shared__ float ls[CC*200];
    __shared__ float lc[NSPIX];
    int tid = threadIdx.x;
    for (int i = tid; i < CC*200; i += 256) ls[i] = 0.f;
    for (int i = tid; i < NSPIX; i += 256) lc[i] = 0.f;
    __syncthreads();

    int t = blockIdx.x / SEG_BLKS_PER_T;
    int chunk = blockIdx.x - t*SEG_BLKS_PER_T;
    int base = chunk*SEG_CHUNK;
    for (int i = tid; i < SEG_CHUNK; i += 256) {
        int hw = base + i;
        int s = spix[t*HWSZ + hw];
        atomicAdd(&lc[s], 1.0f);
        const float* xs = x + (size_t)t*CC*HWSZ + hw;
        #pragma unroll 4
        for (int c = 0; c < CC; ++c) atomicAdd(&ls[c*200 + s], xs[c*HWSZ]);
    }
    __syncthreads();
    for (int i = tid; i < CC*NSPIX; i += 256) {
        int c = i / NSPIX, s = i - c*NSPIX;
        float v = ls[c*200 + s];
        if (v != 0.f) atomicAdd(&sums[(t*NSPIX + s)*CC + c], v);
    }
    for (int i = tid; i < NSPIX; i += 256) {
        float v = lc[i];
        if (v != 0.f) atomicAdd(&cnts[t*NSPIX + i], v);
    }
}

__global__ void k_down(const float* __restrict__ sums, const float* __restrict__ cnts,
                       float* __restrict__ down, float* __restrict__ sq) {
    int ts = blockIdx.x; int c = threadIdx.x;
    float cnt = fmaxf(cnts[ts], 1.0f);
    float d = sums[ts*CC + c] / cnt;
    down[ts*CC + c] = d;
    float v = d*d;
    for (int off = 32; off; off >>= 1) v += __shfl_down(v, off, 64);
    if (c == 0) sq[ts] = v;
}

__global__ void k_pwd(const float* __restrict__ down, const float* __restrict__ sq,
                      float* __restrict__ pwd) {
    int tid = blockIdx.x*256 + threadIdx.x;
    if (tid >= TT*NSPIX*NSPIX) return;
    int t = tid / (NSPIX*NSPIX); int r = tid - t*NSPIX*NSPIX;
    int s = r / NSPIX, u = r - (r / NSPIX)*NSPIX;
    const float* ds = down + (t*NSPIX + s)*CC;
    const float* du = down + (t*NSPIX + u)*CC;
    float dot = 0.f;
    #pragma unroll 4
    for (int c = 0; c < CC; ++c) dot += ds[c]*du[c];
    float v = sq[t*NSPIX + s] + sq[t*NSPIX + u] - 2.f*dot;
    pwd[tid] = fmaxf(v, 0.f);
}

__global__ void k_scale(const float* __restrict__ x, const float* __restrict__ wsc,
                        const float* __restrict__ bsc, float* __restrict__ scale) {
    int pix = blockIdx.x*256 + threadIdx.x;
    if (pix >= TT*HWSZ) return;
    int t = pix / HWSZ, hw = pix - t*HWSZ;
    const float* xs = x + (size_t)t*CC*HWSZ + hw;
    float s1 = 0.f, s2 = 0.f;
    #pragma unroll 4
    for (int c = 0; c < CC; ++c) { float v = xs[c*HWSZ]; s1 += wsc[c]*v; s2 += v*v; }
    float z = s1/(sqrtf(s2) + 1e-10f) + bsc[0];
    float sp_ = (z > 0.f) ? z + log1pf(expf(-z)) : log1pf(expf(z));
    scale[pix] = 10.f*sp_;
}

// MFMA main: per block 8x8 pixel tile; 4 waves = (qo: o-half 0/1, qp: pix-half 0/1).
// Per tap: S_k[o32, pix32] = sum_c W · xpT  (chain of 4 mfma_32x32x16_bf16 over c),
// then acc += rw[k,pix] * S_k.
__global__ __launch_bounds__(256, 4) void k_main(
    const float* __restrict__ x, const int* __restrict__ spix,
    const unsigned short* __restrict__ Wb, const float* __restrict__ b_lin,
    const float* __restrict__ pwd, const float* __restrict__ scale,
    float* __restrict__ out)
{
    __shared__ unsigned short xpT[NPOS*XROW];  // 28224 B, row stride 144 B
    __shared__ unsigned short rwb[K2*64];      // 6272 B (bf16 rw)
    __shared__ int   sp[NPOS];                 // 784 B
    __shared__ float mxp[4*64];                // 1024 B
    __shared__ float mxl[64];                  // 256 B

    int bid = blockIdx.x;
    int t = bid / 400;
    int r = bid - t*400;
    int th0 = (r / 20)*TS, tw0 = (r - (r/20)*20)*TS;
    int tid = threadIdx.y*64 + threadIdx.x;

    // stage spix tile
    for (int i = tid; i < NPOS; i += 256) {
        int rr = reflect(th0 + i/PS - PAD, HH);
        int cc = reflect(tw0 + i%PS - PAD, WW);
        sp[i] = spix[t*HWSZ + rr*WW + cc];
    }
    // stage x tile transposed to bf16 xpT[pos][c]: thread handles (pos, c-pair)
    for (int i = tid; i < NPOS*32; i += 256) {
        int pos = i % NPOS;          // lanes: consecutive pos -> coalesced global reads
        int cp  = i / NPOS;          // 0..31
        int rr = reflect(th0 + pos/PS - PAD, HH);
        int cc = reflect(tw0 + pos%PS - PAD, WW);
        const float* xs = x + ((size_t)t*CC + 2*cp)*HWSZ + rr*WW + cc;
        float v0 = xs[0];
        float v1 = xs[HWSZ];
        unsigned int pk = (unsigned int)f2bf(v0) | ((unsigned int)f2bf(v1) << 16);
        *(unsigned int*)&xpT[pos*XROW + cp*2] = pk;
    }
    __syncthreads();

    // build rw (bf16) + per-pixel max
    int p_ = threadIdx.x;
    int ty = threadIdx.y;
    int py0 = p_ >> 3, px0 = p_ & 7;
    {
        float sc = scale[t*HWSZ + (th0 + py0)*WW + (tw0 + px0)];
        int s0 = sp[(py0 + PAD)*PS + (px0 + PAD)];
        const float* pr = pwd + (t*NSPIX + s0)*NSPIX;
        float pmax = 0.f;
        for (int k = ty; k < K2; k += 4) {
            int di = k/KS, dj = k - di*KS;
            int nb = sp[(py0 + di)*PS + (px0 + dj)];
            float v = expf(-sc * pr[nb]);
            rwb[k*64 + p_] = f2bf(v);
            pmax = fmaxf(pmax, v);
        }
        mxp[ty*64 + p_] = pmax;
    }
    __syncthreads();
    if (ty == 0) {
        float m = fmaxf(fmaxf(mxp[p_], mxp[64 + p_]), fmaxf(mxp[128 + p_], mxp[192 + p_]));
        mxl[p_] = 1.f/(1e-5f + m);
    }
    __syncthreads();
    {
        float s = mxl[p_];
        for (int k = ty; k < K2; k += 4)
            rwb[k*64 + p_] = f2bf(bf2f(rwb[k*64 + p_]) * s);
    }
    __syncthreads();

    // main MFMA loop
    int ln = threadIdx.x;
    int wv = __builtin_amdgcn_readfirstlane(threadIdx.y);
    int qo = wv >> 1, qp = wv & 1;
    int p  = qp*32 + (ln & 31);     // pixel for this lane's B column / C column
    int ppy = p >> 3, ppx = p & 7;
    int k8 = (ln >> 5)*8;           // ushort offset within 16-c chunk

    const unsigned short* Wq = Wb + (size_t)qo*K2*4*512 + ln*8;

    f32x16 acc;
    #pragma unroll
    for (int i = 0; i < 16; ++i) acc[i] = 0.f;

    int di = 0, dj = 0;
    for (int tap = 0; tap < K2; ++tap) {
        const unsigned short* wt = Wq + tap*2048;
        short8 A0 = *(const short8*)(wt);
        short8 A1 = *(const short8*)(wt + 512);
        short8 A2 = *(const short8*)(wt + 1024);
        short8 A3 = *(const short8*)(wt + 1536);

        int pos = (ppy + di)*PS + (ppx + dj);
        const unsigned short* bb = &xpT[pos*XROW + k8];
        short8 B0 = *(const short8*)(bb);
        short8 B1 = *(const short8*)(bb + 16);
        short8 B2 = *(const short8*)(bb + 32);
        short8 B3 = *(const short8*)(bb + 48);

        f32x16 C;
        #pragma unroll
        for (int i = 0; i < 16; ++i) C[i] = 0.f;
        C = __builtin_amdgcn_mfma_f32_32x32x16_bf16(A0, B0, C, 0, 0, 0);
        C = __builtin_amdgcn_mfma_f32_32x32x16_bf16(A1, B1, C, 0, 0, 0);
        C = __builtin_amdgcn_mfma_f32_32x32x16_bf16(A2, B2, C, 0, 0, 0);
        C = __builtin_amdgcn_mfma_f32_32x32x16_bf16(A3, B3, C, 0, 0, 0);

        float rwv = bf2f(rwb[tap*64 + p]);
        #pragma unroll
        for (int i = 0; i < 16; ++i) acc[i] = fmaf(C[i], rwv, acc[i]);

        if (++dj == KS) { dj = 0; ++di; }
    }

    // epilogue: C/D layout col=lane&31 (pixel p), row=(reg&3)+8*(reg>>2)+4*(lane>>5)
    int h = th0 + ppy, w = tw0 + ppx;
    int row_hi = 4*(ln >> 5);
    float* ob = out + (size_t)t*OO*HWSZ + h*WW + w;
    #pragma unroll
    for (int rg = 0; rg < 16; ++rg) {
        int o = qo*32 + (rg & 3) + 8*(rg >> 2) + row_hi;
        ob[(size_t)o*HWSZ] = acc[rg] + b_lin[o];
    }
}

extern "C" void kernel_launch(void* const* d_in, const int* in_sizes, int n_in,
                              void* d_out, int out_size, void* d_ws, size_t ws_size,
                              hipStream_t stream) {
    const float* x    = (const float*)d_in[0];
    const int*   spix = (const int*)d_in[1];
    const float* Wl   = (const float*)d_in[2];
    const float* bl   = (const float*)d_in[3];
    const float* wsc  = (const float*)d_in[4];
    const float* bsc  = (const float*)d_in[5];
    float* out = (float*)d_out;

    float* ws    = (float*)d_ws;
    float* sums  = ws;                          // 25088
    float* cnts  = sums + TT*NSPIX*CC;          // 392
    float* down  = cnts + TT*NSPIX;             // 25088
    float* sq    = down + TT*NSPIX*CC;          // 392
    float* pwd   = sq   + TT*NSPIX;             // 76832
    float* scale = pwd  + TT*NSPIX*NSPIX;       // 51200
    unsigned short* Wb = (unsigned short*)(scale + TT*HWSZ);  // 401408 ushorts

    hipMemsetAsync(sums, 0, (size_t)(TT*NSPIX*CC + TT*NSPIX)*sizeof(float), stream);

    k_wb  <<<(2*K2*4*64*8 + 255)/256, 256, 0, stream>>>(Wl, Wb);
    k_seg <<<TT*SEG_BLKS_PER_T, 256, 0, stream>>>(x, spix, sums, cnts);
    k_down<<<TT*NSPIX, 64, 0, stream>>>(sums, cnts, down, sq);
    k_pwd <<<(TT*NSPIX*NSPIX + 255)/256, 256, 0, stream>>>(down, sq, pwd);
    k_scale<<<(TT*HWSZ + 255)/256, 256, 0, stream>>>(x, wsc, bsc, scale);

    dim3 blk(64, 4, 1);
    k_main<<<TT*(HH/TS)*(WW/TS), blk, 0, stream>>>(x, spix, Wb, bl, pwd, scale, out);
}

// Round 4
// 166.729 us; speedup vs baseline: 5.5556x; 1.6077x over previous
//
#include <hip/hip_runtime.h>
#include <math.h>

#define TT 2
#define CC 64
#define HH 160
#define WW 160
#define KS 7
#define K2 49
#define NSPIX 196
#define HWSZ (HH*WW)
#define PAD 3
#define OO 64
#define FANIN (CC*K2)
#define TS 8
#define PS (TS+KS-1)   // 14
#define NPOS (PS*PS)   // 196
#define XROW 72        // bf16 elems per padded row (144 B)

#define NCHUNK 50      // pixel chunks per t (512 pixels each)
#define CHUNKPIX 512
#define NCG 8          // channel groups (8 ch each)

typedef short short8 __attribute__((ext_vector_type(8)));
typedef float f32x16 __attribute__((ext_vector_type(16)));

__device__ __forceinline__ int reflect(int i, int n) {
    if (i < 0) i = -i;
    if (i >= n) i = 2*n - 2 - i;
    return i;
}

__device__ __forceinline__ unsigned short f2bf(float f) {
    unsigned int u = __float_as_uint(f);
    unsigned int r = (u + 0x7FFFu + ((u >> 16) & 1u)) >> 16;
    return (unsigned short)r;
}
__device__ __forceinline__ float bf2f(unsigned short s) {
    return __uint_as_float(((unsigned int)s) << 16);
}

// Build Wb in 32x32x16 bf16 A-fragment order:
// flat = (((qo*49+tap)*4+kc)*64+ln)*8+j ; o=qo*32+(ln&31); c=kc*16+(ln>>5)*8+j
__global__ void k_wb(const float* __restrict__ Wl, unsigned short* __restrict__ Wb) {
    int idx = blockIdx.x*256 + threadIdx.x;
    if (idx >= 2*K2*4*64*8) return;
    int j   = idx & 7;
    int ln  = (idx >> 3) & 63;
    int kc  = (idx >> 9) & 3;
    int tap = (idx >> 11) % K2;
    int qo  = idx / (K2 << 11);
    int o = qo*32 + (ln & 31);
    int c = kc*16 + (ln >> 5)*8 + j;
    Wb[idx] = f2bf(Wl[o*FANIN + c*K2 + tap]);
}

// phase-1 segment sums: 800 blocks = t(2) x chunk(50) x cgroup(8).
// LDS-privatized [8ch][200], deterministic flush to partials[t][chunk][s][c].
__global__ __launch_bounds__(256) void k_seg(const float* __restrict__ x,
                                             const int* __restrict__ spix,
                                             float* __restrict__ partials,
                                             float* __restrict__ cntp) {
    __shared__ float ls[8*200];
    __shared__ float lcnt[200];
    int tid = threadIdx.x;
    int cg = blockIdx.x & 7;
    int rest = blockIdx.x >> 3;
    int ch = rest % NCHUNK;
    int t  = rest / NCHUNK;

    for (int i = tid; i < 8*200; i += 256) ls[i] = 0.f;
    if (cg == 0) for (int i = tid; i < 200; i += 256) lcnt[i] = 0.f;
    __syncthreads();

    int base = ch*CHUNKPIX;
    const float* xb = x + ((size_t)t*CC + cg*8)*HWSZ;
    #pragma unroll
    for (int i = 0; i < CHUNKPIX; i += 256) {
        int pix = base + i + tid;
        int s = spix[t*HWSZ + pix];
        if (cg == 0) atomicAdd(&lcnt[s], 1.0f);
        #pragma unroll
        for (int j = 0; j < 8; ++j) atomicAdd(&ls[j*200 + s], xb[(size_t)j*HWSZ + pix]);
    }
    __syncthreads();

    float* pb = partials + ((size_t)(t*NCHUNK + ch)*NSPIX)*CC + cg*8;
    for (int i = tid; i < 8*NSPIX; i += 256) {
        int s = i >> 3, j = i & 7;
        pb[s*CC + j] = ls[j*200 + s];
    }
    if (cg == 0)
        for (int i = tid; i < NSPIX; i += 256)
            cntp[(t*NCHUNK + ch)*NSPIX + i] = lcnt[i];
}

// reduce partials -> down, sq (one wave per (t,s); lane = c)
__global__ __launch_bounds__(256) void k_red(const float* __restrict__ partials,
                                             const float* __restrict__ cntp,
                                             float* __restrict__ down,
                                             float* __restrict__ sq) {
    int ts = blockIdx.x*4 + threadIdx.y;
    if (ts >= TT*NSPIX) return;
    int t = ts / NSPIX, s = ts - t*NSPIX;
    int c = threadIdx.x;

    const float* pb = partials + ((size_t)t*NCHUNK*NSPIX + s)*CC + c;
    float acc = 0.f;
    #pragma unroll 10
    for (int ch = 0; ch < NCHUNK; ++ch) acc += pb[(size_t)ch*NSPIX*CC];

    float cv = (c < NCHUNK) ? cntp[(t*NCHUNK + c)*NSPIX + s] : 0.f;
    #pragma unroll
    for (int off = 1; off < 64; off <<= 1) cv += __shfl_xor(cv, off, 64);

    float d = acc / fmaxf(cv, 1.0f);
    down[ts*CC + c] = d;
    float v = d*d;
    #pragma unroll
    for (int off = 1; off < 64; off <<= 1) v += __shfl_xor(v, off, 64);
    if (c == 0) sq[ts] = v;
}

__global__ void k_pwd(const float* __restrict__ down, const float* __restrict__ sq,
                      float* __restrict__ pwd) {
    int tid = blockIdx.x*256 + threadIdx.x;
    if (tid >= TT*NSPIX*NSPIX) return;
    int t = tid / (NSPIX*NSPIX); int r = tid - t*NSPIX*NSPIX;
    int s = r / NSPIX, u = r - (r / NSPIX)*NSPIX;
    const float* ds = down + (t*NSPIX + s)*CC;
    const float* du = down + (t*NSPIX + u)*CC;
    float dot = 0.f;
    #pragma unroll 4
    for (int c = 0; c < CC; ++c) dot += ds[c]*du[c];
    float v = sq[t*NSPIX + s] + sq[t*NSPIX + u] - 2.f*dot;
    pwd[tid] = fmaxf(v, 0.f);
}

__global__ void k_scale(const float* __restrict__ x, const float* __restrict__ wsc,
                        const float* __restrict__ bsc, float* __restrict__ scale) {
    int pix = blockIdx.x*256 + threadIdx.x;
    if (pix >= TT*HWSZ) return;
    int t = pix / HWSZ, hw = pix - t*HWSZ;
    const float* xs = x + (size_t)t*CC*HWSZ + hw;
    float s1 = 0.f, s2 = 0.f;
    #pragma unroll 8
    for (int c = 0; c < CC; ++c) { float v = xs[c*HWSZ]; s1 += wsc[c]*v; s2 += v*v; }
    float z = s1/(sqrtf(s2) + 1e-10f) + bsc[0];
    float sp_ = (z > 0.f) ? z + log1pf(expf(-z)) : log1pf(expf(z));
    scale[pix] = 10.f*sp_;
}

// MFMA main: per block 8x8 pixel tile; 4 waves = (qo: o-half, qp: pix-half).
__global__ __launch_bounds__(256, 4) void k_main(
    const float* __restrict__ x, const int* __restrict__ spix,
    const unsigned short* __restrict__ Wb, const float* __restrict__ b_lin,
    const float* __restrict__ pwd, const float* __restrict__ scale,
    float* __restrict__ out)
{
    __shared__ unsigned short xpT[NPOS*XROW];
    __shared__ unsigned short rwb[K2*64];
    __shared__ int   sp[NPOS];
    __shared__ float mxp[4*64];
    __shared__ float mxl[64];

    int bid = blockIdx.x;
    int t = bid / 400;
    int r = bid - t*400;
    int th0 = (r / 20)*TS, tw0 = (r - (r/20)*20)*TS;
    int tid = threadIdx.y*64 + threadIdx.x;

    for (int i = tid; i < NPOS; i += 256) {
        int rr = reflect(th0 + i/PS - PAD, HH);
        int cc = reflect(tw0 + i%PS - PAD, WW);
        sp[i] = spix[t*HWSZ + rr*WW + cc];
    }
    for (int i = tid; i < NPOS*32; i += 256) {
        int pos = i % NPOS;
        int cp  = i / NPOS;
        int rr = reflect(th0 + pos/PS - PAD, HH);
        int cc = reflect(tw0 + pos%PS - PAD, WW);
        const float* xs = x + ((size_t)t*CC + 2*cp)*HWSZ + rr*WW + cc;
        float v0 = xs[0];
        float v1 = xs[HWSZ];
        unsigned int pk = (unsigned int)f2bf(v0) | ((unsigned int)f2bf(v1) << 16);
        *(unsigned int*)&xpT[pos*XROW + cp*2] = pk;
    }
    __syncthreads();

    int p_ = threadIdx.x;
    int ty = threadIdx.y;
    int py0 = p_ >> 3, px0 = p_ & 7;
    {
        float sc = scale[t*HWSZ + (th0 + py0)*WW + (tw0 + px0)];
        int s0 = sp[(py0 + PAD)*PS + (px0 + PAD)];
        const float* pr = pwd + (t*NSPIX + s0)*NSPIX;
        float pmax = 0.f;
        for (int k = ty; k < K2; k += 4) {
            int di = k/KS, dj = k - di*KS;
            int nb = sp[(py0 + di)*PS + (px0 + dj)];
            float v = expf(-sc * pr[nb]);
            rwb[k*64 + p_] = f2bf(v);
            pmax = fmaxf(pmax, v);
        }
        mxp[ty*64 + p_] = pmax;
    }
    __syncthreads();
    if (ty == 0) {
        float m = fmaxf(fmaxf(mxp[p_], mxp[64 + p_]), fmaxf(mxp[128 + p_], mxp[192 + p_]));
        mxl[p_] = 1.f/(1e-5f + m);
    }
    __syncthreads();
    {
        float s = mxl[p_];
        for (int k = ty; k < K2; k += 4)
            rwb[k*64 + p_] = f2bf(bf2f(rwb[k*64 + p_]) * s);
    }
    __syncthreads();

    int ln = threadIdx.x;
    int wv = __builtin_amdgcn_readfirstlane(threadIdx.y);
    int qo = wv >> 1, qp = wv & 1;
    int p  = qp*32 + (ln & 31);
    int ppy = p >> 3, ppx = p & 7;
    int k8 = (ln >> 5)*8;

    const unsigned short* Wq = Wb + (size_t)qo*K2*4*512 + ln*8;

    f32x16 acc;
    #pragma unroll
    for (int i = 0; i < 16; ++i) acc[i] = 0.f;

    int di = 0, dj = 0;
    for (int tap = 0; tap < K2; ++tap) {
        const unsigned short* wt = Wq + tap*2048;
        short8 A0 = *(const short8*)(wt);
        short8 A1 = *(const short8*)(wt + 512);
        short8 A2 = *(const short8*)(wt + 1024);
        short8 A3 = *(const short8*)(wt + 1536);

        int pos = (ppy + di)*PS + (ppx + dj);
        const unsigned short* bb = &xpT[pos*XROW + k8];
        short8 B0 = *(const short8*)(bb);
        short8 B1 = *(const short8*)(bb + 16);
        short8 B2 = *(const short8*)(bb + 32);
        short8 B3 = *(const short8*)(bb + 48);

        f32x16 C;
        #pragma unroll
        for (int i = 0; i < 16; ++i) C[i] = 0.f;
        C = __builtin_amdgcn_mfma_f32_32x32x16_bf16(A0, B0, C, 0, 0, 0);
        C = __builtin_amdgcn_mfma_f32_32x32x16_bf16(A1, B1, C, 0, 0, 0);
        C = __builtin_amdgcn_mfma_f32_32x32x16_bf16(A2, B2, C, 0, 0, 0);
        C = __builtin_amdgcn_mfma_f32_32x32x16_bf16(A3, B3, C, 0, 0, 0);

        float rwv = bf2f(rwb[tap*64 + p]);
        #pragma unroll
        for (int i = 0; i < 16; ++i) acc[i] = fmaf(C[i], rwv, acc[i]);

        if (++dj == KS) { dj = 0; ++di; }
    }

    int h = th0 + ppy, w = tw0 + ppx;
    int row_hi = 4*(ln >> 5);
    float* ob = out + (size_t)t*OO*HWSZ + h*WW + w;
    #pragma unroll
    for (int rg = 0; rg < 16; ++rg) {
        int o = qo*32 + (rg & 3) + 8*(rg >> 2) + row_hi;
        ob[(size_t)o*HWSZ] = acc[rg] + b_lin[o];
    }
}

extern "C" void kernel_launch(void* const* d_in, const int* in_sizes, int n_in,
                              void* d_out, int out_size, void* d_ws, size_t ws_size,
                              hipStream_t stream) {
    const float* x    = (const float*)d_in[0];
    const int*   spix = (const int*)d_in[1];
    const float* Wl   = (const float*)d_in[2];
    const float* bl   = (const float*)d_in[3];
    const float* wsc  = (const float*)d_in[4];
    const float* bsc  = (const float*)d_in[5];
    float* out = (float*)d_out;

    float* ws    = (float*)d_ws;
    float* down  = ws;                           // 25088
    float* sq    = down + TT*NSPIX*CC;           // 392
    float* pwd   = sq   + TT*NSPIX;              // 76832
    float* scale = pwd  + TT*NSPIX*NSPIX;        // 51200
    float* cntp  = scale + TT*HWSZ;              // 19600
    float* parts = cntp + TT*NCHUNK*NSPIX;       // 1254400
    unsigned short* Wb = (unsigned short*)(parts + (size_t)TT*NCHUNK*NSPIX*CC);

    k_wb  <<<(2*K2*4*64*8 + 255)/256, 256, 0, stream>>>(Wl, Wb);
    k_seg <<<TT*NCHUNK*NCG, 256, 0, stream>>>(x, spix, parts, cntp);
    {
        dim3 blk(64, 4, 1);
        k_red <<<(TT*NSPIX + 3)/4, blk, 0, stream>>>(parts, cntp, down, sq);
    }
    k_pwd <<<(TT*NSPIX*NSPIX + 255)/256, 256, 0, stream>>>(down, sq, pwd);
    k_scale<<<(TT*HWSZ + 255)/256, 256, 0, stream>>>(x, wsc, bsc, scale);

    dim3 blk(64, 4, 1);
    k_main<<<TT*(HH/TS)*(WW/TS), blk, 0, stream>>>(x, spix, Wb, bl, pwd, scale, out);
}

// Round 5
// 162.523 us; speedup vs baseline: 5.6994x; 1.0259x over previous
//
#include <hip/hip_runtime.h>
#include <math.h>

#define TT 2
#define CC 64
#define HH 160
#define WW 160
#define KS 7
#define K2 49
#define NSPIX 196
#define HWSZ (HH*WW)
#define PAD 3
#define OO 64
#define FANIN (CC*K2)
#define TS 8
#define PS (TS+KS-1)   // 14
#define NPOS (PS*PS)   // 196

#define NCHUNK 50
#define CHUNKPIX 512
#define NCG 8

typedef short short8 __attribute__((ext_vector_type(8)));
typedef float f32x16 __attribute__((ext_vector_type(16)));

__device__ __forceinline__ int reflect(int i, int n) {
    if (i < 0) i = -i;
    if (i >= n) i = 2*n - 2 - i;
    return i;
}

__device__ __forceinline__ unsigned short f2bf(float f) {
    unsigned int u = __float_as_uint(f);
    unsigned int r = (u + 0x7FFFu + ((u >> 16) & 1u)) >> 16;
    return (unsigned short)r;
}
__device__ __forceinline__ float bf2f(unsigned short s) {
    return __uint_as_float(((unsigned int)s) << 16);
}

// fused prep: blocks [0,800) seg-partials; [800,1000) scale; [1000,1196) Wb build
__global__ __launch_bounds__(256) void k_prep(const float* __restrict__ x,
                                              const int* __restrict__ spix,
                                              const float* __restrict__ Wl,
                                              const float* __restrict__ wsc,
                                              const float* __restrict__ bsc,
                                              float* __restrict__ partials,
                                              float* __restrict__ cntp,
                                              float* __restrict__ scale,
                                              unsigned short* __restrict__ Wb) {
    __shared__ float ls[8*200];
    __shared__ float lcnt[200];
    int bid = blockIdx.x;
    int tid = threadIdx.x;

    if (bid < 800) {
        int cg = bid & 7;
        int rest = bid >> 3;
        int ch = rest % NCHUNK;
        int t  = rest / NCHUNK;

        for (int i = tid; i < 8*200; i += 256) ls[i] = 0.f;
        if (cg == 0) for (int i = tid; i < 200; i += 256) lcnt[i] = 0.f;
        __syncthreads();

        int base = ch*CHUNKPIX;
        const float* xb = x + ((size_t)t*CC + cg*8)*HWSZ;
        #pragma unroll
        for (int i = 0; i < CHUNKPIX; i += 256) {
            int pix = base + i + tid;
            int s = spix[t*HWSZ + pix];
            if (cg == 0) atomicAdd(&lcnt[s], 1.0f);
            #pragma unroll
            for (int j = 0; j < 8; ++j) atomicAdd(&ls[j*200 + s], xb[(size_t)j*HWSZ + pix]);
        }
        __syncthreads();

        float* pb = partials + ((size_t)(t*NCHUNK + ch)*NSPIX)*CC + cg*8;
        for (int i = tid; i < 8*NSPIX; i += 256) {
            int s = i >> 3, j = i & 7;
            pb[s*CC + j] = ls[j*200 + s];
        }
        if (cg == 0)
            for (int i = tid; i < NSPIX; i += 256)
                cntp[(t*NCHUNK + ch)*NSPIX + i] = lcnt[i];
    } else if (bid < 1000) {
        int pix = (bid - 800)*256 + tid;
        if (pix < TT*HWSZ) {
            int t = pix / HWSZ, hw = pix - t*HWSZ;
            const float* xs = x + (size_t)t*CC*HWSZ + hw;
            float s1 = 0.f, s2 = 0.f;
            #pragma unroll 8
            for (int c = 0; c < CC; ++c) { float v = xs[c*HWSZ]; s1 += wsc[c]*v; s2 += v*v; }
            float z = s1/(sqrtf(s2) + 1e-10f) + bsc[0];
            float sp_ = (z > 0.f) ? z + log1pf(expf(-z)) : log1pf(expf(z));
            scale[pix] = 10.f*sp_;
        }
    } else {
        // Wb row = ((qo*49+tap)*4+kc)*64 + ln ; elems j=0..7: c = kc*16+(ln>>5)*8+j
        int row = (bid - 1000)*256 + tid;
        if (row < 2*K2*4*64) {
            int ln  = row & 63;
            int kc  = (row >> 6) & 3;
            int tq  = row >> 8;
            int tap = tq % K2;
            int qo  = tq / K2;
            int o = qo*32 + (ln & 31);
            int cb = kc*16 + (ln >> 5)*8;
            unsigned short* dst = Wb + (size_t)row*8;
            const float* src = Wl + (size_t)o*FANIN + tap;
            #pragma unroll
            for (int j = 0; j < 8; ++j) dst[j] = f2bf(src[(size_t)(cb + j)*K2]);
        }
    }
}

// reduce partials -> down, sq (one wave per (t,s); lane = c)
__global__ __launch_bounds__(256) void k_red(const float* __restrict__ partials,
                                             const float* __restrict__ cntp,
                                             float* __restrict__ down,
                                             float* __restrict__ sq) {
    int ts = blockIdx.x*4 + threadIdx.y;
    if (ts >= TT*NSPIX) return;
    int t = ts / NSPIX, s = ts - t*NSPIX;
    int c = threadIdx.x;

    const float* pb = partials + ((size_t)t*NCHUNK*NSPIX + s)*CC + c;
    float acc = 0.f;
    #pragma unroll 10
    for (int ch = 0; ch < NCHUNK; ++ch) acc += pb[(size_t)ch*NSPIX*CC];

    float cv = (c < NCHUNK) ? cntp[(t*NCHUNK + c)*NSPIX + s] : 0.f;
    #pragma unroll
    for (int off = 1; off < 64; off <<= 1) cv += __shfl_xor(cv, off, 64);

    float d = acc / fmaxf(cv, 1.0f);
    down[ts*CC + c] = d;
    float v = d*d;
    #pragma unroll
    for (int off = 1; off < 64; off <<= 1) v += __shfl_xor(v, off, 64);
    if (c == 0) sq[ts] = v;
}

__global__ void k_pwd(const float* __restrict__ down, const float* __restrict__ sq,
                      float* __restrict__ pwd) {
    int tid = blockIdx.x*256 + threadIdx.x;
    if (tid >= TT*NSPIX*NSPIX) return;
    int t = tid / (NSPIX*NSPIX); int r = tid - t*NSPIX*NSPIX;
    int s = r / NSPIX, u = r - (r / NSPIX)*NSPIX;
    const float* ds = down + (t*NSPIX + s)*CC;
    const float* du = down + (t*NSPIX + u)*CC;
    float dot = 0.f;
    #pragma unroll 4
    for (int c = 0; c < CC; ++c) dot += ds[c]*du[c];
    float v = sq[t*NSPIX + s] + sq[t*NSPIX + u] - 2.f*dot;
    pwd[tid] = fmaxf(v, 0.f);
}

// MFMA main. Block = 8x8 pixel tile, 4 waves = (kh: K-half 0/1) x (qp: pix-half 0/1).
// Each wave: M=64 (both o-halves, 2 C chains), K=32 (its 2 kc chunks) -> only
// 2 ds_read_b128 per tap. xpT is XOR-swizzled (16B chunk ^ (pos&7)) -> conflict-free.
// Cross-wave K-reduction via LDS at the end.
__global__ __launch_bounds__(256, 4) void k_main(
    const float* __restrict__ x, const int* __restrict__ spix,
    const unsigned short* __restrict__ Wb, const float* __restrict__ b_lin,
    const float* __restrict__ pwd, const float* __restrict__ scale,
    float* __restrict__ out)
{
    __shared__ unsigned short xpT[NPOS*64];   // 25088 B, swizzled
    __shared__ unsigned short rwb[K2*64];     // 6272 B
    __shared__ int   sp[NPOS];                // 784 B
    __shared__ float mxp[4*64];
    __shared__ float mxl[64];

    int bid = blockIdx.x;
    int t = bid / 400;
    int r = bid - t*400;
    int th0 = (r / 20)*TS, tw0 = (r - (r/20)*20)*TS;
    int tid = threadIdx.y*64 + threadIdx.x;

    for (int i = tid; i < NPOS; i += 256) {
        int rr = reflect(th0 + i/PS - PAD, HH);
        int cc = reflect(tw0 + i%PS - PAD, WW);
        sp[i] = spix[t*HWSZ + rr*WW + cc];
    }
    // stage x -> bf16 xpT[pos][c] with 16B-chunk XOR swizzle
    for (int i = tid; i < NPOS*32; i += 256) {
        int pos = i % NPOS;
        int cp  = i / NPOS;          // channel pair 0..31
        int rr = reflect(th0 + pos/PS - PAD, HH);
        int cc = reflect(tw0 + pos%PS - PAD, WW);
        const float* xs = x + ((size_t)t*CC + 2*cp)*HWSZ + rr*WW + cc;
        float v0 = xs[0];
        float v1 = xs[HWSZ];
        unsigned int pk = (unsigned int)f2bf(v0) | ((unsigned int)f2bf(v1) << 16);
        int idx = pos*64 + (((cp >> 2) ^ (pos & 7)) << 3) + (cp & 3)*2;
        *(unsigned int*)&xpT[idx] = pk;
    }
    __syncthreads();

    int p_ = threadIdx.x;
    int ty = threadIdx.y;
    int py0 = p_ >> 3, px0 = p_ & 7;
    {
        float sc = scale[t*HWSZ + (th0 + py0)*WW + (tw0 + px0)];
        int s0 = sp[(py0 + PAD)*PS + (px0 + PAD)];
        const float* pr = pwd + (t*NSPIX + s0)*NSPIX;
        float pmax = 0.f;
        for (int k = ty; k < K2; k += 4) {
            int di = k/KS, dj = k - di*KS;
            int nb = sp[(py0 + di)*PS + (px0 + dj)];
            float v = expf(-sc * pr[nb]);
            rwb[k*64 + p_] = f2bf(v);
            pmax = fmaxf(pmax, v);
        }
        mxp[ty*64 + p_] = pmax;
    }
    __syncthreads();
    if (ty == 0) {
        float m = fmaxf(fmaxf(mxp[p_], mxp[64 + p_]), fmaxf(mxp[128 + p_], mxp[192 + p_]));
        mxl[p_] = 1.f/(1e-5f + m);
    }
    __syncthreads();
    {
        float s = mxl[p_];
        for (int k = ty; k < K2; k += 4)
            rwb[k*64 + p_] = f2bf(bf2f(rwb[k*64 + p_]) * s);
    }
    __syncthreads();

    int ln = threadIdx.x;
    int wv = __builtin_amdgcn_readfirstlane(threadIdx.y);
    int qp = wv & 1, kh = wv >> 1;
    int p  = qp*32 + (ln & 31);
    int ppy = p >> 3, ppx = p & 7;
    int kc0 = 2*kh, kc1 = 2*kh + 1;
    int lhi = ln >> 5;               // K sub-half within instruction

    // A frag bases: ((qo*49+tap)*4+kc)*512 + ln*8
    const unsigned short* A00b = Wb + (size_t)kc0*512 + ln*8;            // qo=0
    const unsigned short* A10b = A00b + (size_t)K2*4*512;                // qo=1

    f32x16 Czero;
    #pragma unroll
    for (int i = 0; i < 16; ++i) Czero[i] = 0.f;
    f32x16 acc0 = Czero, acc1 = Czero;

    int jc0 = 2*kc0 + lhi, jc1 = 2*kc1 + lhi;   // xpT 16B-chunk indices

    int di = 0, dj = 0;
    #pragma unroll 7
    for (int tap = 0; tap < K2; ++tap) {
        const unsigned short* a0 = A00b + tap*2048;
        short8 A00 = *(const short8*)(a0);
        short8 A01 = *(const short8*)(a0 + 512);
        const unsigned short* a1 = A10b + tap*2048;
        short8 A10 = *(const short8*)(a1);
        short8 A11 = *(const short8*)(a1 + 512);

        int pos = (ppy + di)*PS + (ppx + dj);
        int sw  = pos & 7;
        const unsigned short* bbase = &xpT[pos*64];
        short8 B0 = *(const short8*)(bbase + ((jc0 ^ sw) << 3));
        short8 B1 = *(const short8*)(bbase + ((jc1 ^ sw) << 3));

        f32x16 C0 = __builtin_amdgcn_mfma_f32_32x32x16_bf16(A00, B0, Czero, 0, 0, 0);
        C0 = __builtin_amdgcn_mfma_f32_32x32x16_bf16(A01, B1, C0, 0, 0, 0);
        f32x16 C1 = __builtin_amdgcn_mfma_f32_32x32x16_bf16(A10, B0, Czero, 0, 0, 0);
        C1 = __builtin_amdgcn_mfma_f32_32x32x16_bf16(A11, B1, C1, 0, 0, 0);

        float rwv = bf2f(rwb[tap*64 + p]);
        #pragma unroll
        for (int i = 0; i < 16; ++i) acc0[i] = fmaf(C0[i], rwv, acc0[i]);
        #pragma unroll
        for (int i = 0; i < 16; ++i) acc1[i] = fmaf(C1[i], rwv, acc1[i]);

        if (++dj == KS) { dj = 0; ++di; }
    }

    // cross-wave K-reduction: kh=1 waves dump, kh=0 waves add + store.
    __syncthreads();
    float* red = (float*)xpT;   // 32 x 128 floats = 16 KB (element-major: conflict-free)
    if (kh == 1) {
        #pragma unroll
        for (int i = 0; i < 16; ++i) {
            red[i*128 + qp*64 + ln]        = acc0[i];
            red[(16 + i)*128 + qp*64 + ln] = acc1[i];
        }
    }
    __syncthreads();
    if (kh == 0) {
        int h = th0 + ppy, w = tw0 + ppx;
        int row_hi = 4*lhi;
        float* ob = out + (size_t)t*OO*HWSZ + h*WW + w;
        #pragma unroll
        for (int rg = 0; rg < 16; ++rg) {
            float v0 = acc0[rg] + red[rg*128 + qp*64 + ln];
            float v1 = acc1[rg] + red[(16 + rg)*128 + qp*64 + ln];
            int o0 = (rg & 3) + 8*(rg >> 2) + row_hi;
            int o1 = 32 + o0;
            ob[(size_t)o0*HWSZ] = v0 + b_lin[o0];
            ob[(size_t)o1*HWSZ] = v1 + b_lin[o1];
        }
    }
}

extern "C" void kernel_launch(void* const* d_in, const int* in_sizes, int n_in,
                              void* d_out, int out_size, void* d_ws, size_t ws_size,
                              hipStream_t stream) {
    const float* x    = (const float*)d_in[0];
    const int*   spix = (const int*)d_in[1];
    const float* Wl   = (const float*)d_in[2];
    const float* bl   = (const float*)d_in[3];
    const float* wsc  = (const float*)d_in[4];
    const float* bsc  = (const float*)d_in[5];
    float* out = (float*)d_out;

    float* ws    = (float*)d_ws;
    float* down  = ws;                           // 25088
    float* sq    = down + TT*NSPIX*CC;           // 392
    float* pwd   = sq   + TT*NSPIX;              // 76832
    float* scale = pwd  + TT*NSPIX*NSPIX;        // 51200
    float* cntp  = scale + TT*HWSZ;              // 19600
    float* parts = cntp + TT*NCHUNK*NSPIX;       // 1254400
    unsigned short* Wb = (unsigned short*)(parts + (size_t)TT*NCHUNK*NSPIX*CC);

    k_prep<<<1196, 256, 0, stream>>>(x, spix, Wl, wsc, bsc, parts, cntp, scale, Wb);
    {
        dim3 blk(64, 4, 1);
        k_red <<<(TT*NSPIX + 3)/4, blk, 0, stream>>>(parts, cntp, down, sq);
    }
    k_pwd <<<(TT*NSPIX*NSPIX + 255)/256, 256, 0, stream>>>(down, sq, pwd);

    dim3 blk(64, 4, 1);
    k_main<<<TT*(HH/TS)*(WW/TS), blk, 0, stream>>>(x, spix, Wb, bl, pwd, scale, out);
}